// Round 1
// baseline (828.961 us; speedup 1.0000x reference)
//
#include <hip/hip_runtime.h>

#define D_MODEL 512
#define DINNER  1024
#define DSTATE  64
#define DTRANK  32
#define BSZ     2
#define NLEN    2048
#define NROWS   (BSZ*NLEN)   // 4096
#define XDBL_W  (DTRANK + 2*DSTATE)  // 160

// ---------------- LayerNorm: one wave per row ----------------
__global__ __launch_bounds__(256) void ln_kernel(const float* __restrict__ x,
        const float* __restrict__ w, const float* __restrict__ bvec,
        float* __restrict__ xn) {
    const int wid = threadIdx.x >> 6, lane = threadIdx.x & 63;
    const int row = (blockIdx.x << 2) + wid;
    const float4* xp = (const float4*)(x + (size_t)row * D_MODEL);
    float4 v0 = xp[lane], v1 = xp[lane + 64];
    float s = v0.x + v0.y + v0.z + v0.w + v1.x + v1.y + v1.z + v1.w;
    float q = v0.x*v0.x + v0.y*v0.y + v0.z*v0.z + v0.w*v0.w
            + v1.x*v1.x + v1.y*v1.y + v1.z*v1.z + v1.w*v1.w;
    #pragma unroll
    for (int m = 32; m; m >>= 1) { s += __shfl_xor(s, m); q += __shfl_xor(q, m); }
    const float mean = s * (1.f / D_MODEL);
    const float var  = q * (1.f / D_MODEL) - mean * mean;
    const float rstd = rsqrtf(var + 1e-5f);
    const float4* wp = (const float4*)w;
    const float4* bp = (const float4*)bvec;
    float4 w0 = wp[lane], w1 = wp[lane + 64], b0 = bp[lane], b1 = bp[lane + 64];
    float4 o0, o1;
    o0.x = (v0.x - mean) * rstd * w0.x + b0.x;
    o0.y = (v0.y - mean) * rstd * w0.y + b0.y;
    o0.z = (v0.z - mean) * rstd * w0.z + b0.z;
    o0.w = (v0.w - mean) * rstd * w0.w + b0.w;
    o1.x = (v1.x - mean) * rstd * w1.x + b1.x;
    o1.y = (v1.y - mean) * rstd * w1.y + b1.y;
    o1.z = (v1.z - mean) * rstd * w1.z + b1.z;
    o1.w = (v1.w - mean) * rstd * w1.w + b1.w;
    float4* op = (float4*)(xn + (size_t)row * D_MODEL);
    op[lane] = o0; op[lane + 64] = o1;
}

// ------------- generic NT SGEMM: C(M,N) = A(M,K) * B(N,K)^T -------------
// BM=128, BN=64, BK=8; 256 threads; 8x4 micro-tile (rows split ty*4 / 64+ty*4).
// Epilogue splits cols: col < split -> out0 (ld=split), else out1 (ld=N-split).
__global__ __launch_bounds__(256) void gemm_nt(const float* __restrict__ A,
        const float* __restrict__ B, int M, int N, int K,
        float* __restrict__ out0, float* __restrict__ out1, int split) {
    __shared__ float sA[8][132];
    __shared__ float sB[8][68];
    const int tid = threadIdx.x;
    const int m0 = blockIdx.y * 128, n0 = blockIdx.x * 64;
    const int lr = tid >> 1, lc = (tid & 1) << 2;
    const int ty = tid >> 4, tx = tid & 15;
    float acc[2][4][4] = {};
    for (int k0 = 0; k0 < K; k0 += 8) {
        float4 av = *(const float4*)(A + (size_t)(m0 + lr) * K + k0 + lc);
        float4 bv = make_float4(0.f, 0.f, 0.f, 0.f);
        if (tid < 128) {
            const int brow = n0 + lr;
            if (brow < N) bv = *(const float4*)(B + (size_t)brow * K + k0 + lc);
        }
        __syncthreads();
        sA[lc + 0][lr] = av.x; sA[lc + 1][lr] = av.y;
        sA[lc + 2][lr] = av.z; sA[lc + 3][lr] = av.w;
        if (tid < 128) {
            sB[lc + 0][lr] = bv.x; sB[lc + 1][lr] = bv.y;
            sB[lc + 2][lr] = bv.z; sB[lc + 3][lr] = bv.w;
        }
        __syncthreads();
        #pragma unroll
        for (int kk = 0; kk < 8; ++kk) {
            float4 a0 = *(const float4*)&sA[kk][ty << 2];
            float4 a1 = *(const float4*)&sA[kk][64 + (ty << 2)];
            float4 bb = *(const float4*)&sB[kk][tx << 2];
            const float aa[2][4] = {{a0.x, a0.y, a0.z, a0.w}, {a1.x, a1.y, a1.z, a1.w}};
            const float bbv[4] = {bb.x, bb.y, bb.z, bb.w};
            #pragma unroll
            for (int ih = 0; ih < 2; ++ih)
                #pragma unroll
                for (int il = 0; il < 4; ++il)
                    #pragma unroll
                    for (int jl = 0; jl < 4; ++jl)
                        acc[ih][il][jl] = fmaf(aa[ih][il], bbv[jl], acc[ih][il][jl]);
        }
    }
    const int col = n0 + (tx << 2);
    if (col < N) {
        #pragma unroll
        for (int ih = 0; ih < 2; ++ih)
            #pragma unroll
            for (int il = 0; il < 4; ++il) {
                const int row = m0 + (ih << 6) + (ty << 2) + il;
                float4 v = make_float4(acc[ih][il][0], acc[ih][il][1],
                                       acc[ih][il][2], acc[ih][il][3]);
                if (col < split)
                    *(float4*)(out0 + (size_t)row * split + col) = v;
                else
                    *(float4*)(out1 + (size_t)row * (N - split) + (col - split)) = v;
            }
    }
}

// ---------------- causal depthwise conv (k=4) + SiLU ----------------
__global__ __launch_bounds__(256) void conv_kernel(const float* __restrict__ xr,
        const float* __restrict__ cw, const float* __restrict__ cb,
        float* __restrict__ xi) {
    const int g = blockIdx.x * 256 + threadIdx.x;  // < BSZ*NLEN*DINNER
    const int d = g & (DINNER - 1);
    const int n = (g >> 10) & (NLEN - 1);
    const float4 wv = *(const float4*)(cw + d * 4);  // taps k=0..3 -> n-3..n
    const float* p = xr + g;
    float acc = cb[d];
    acc = fmaf(wv.w, p[0], acc);
    if (n >= 1) acc = fmaf(wv.z, p[-DINNER], acc);
    if (n >= 2) acc = fmaf(wv.y, p[-2 * DINNER], acc);
    if (n >= 3) acc = fmaf(wv.x, p[-3 * DINNER], acc);
    xi[g] = acc / (1.f + expf(-acc));
}

// ---------------- dt = softplus(dtr @ W^T + b), one row per block ----------------
__global__ __launch_bounds__(256) void dt_kernel(const float* __restrict__ xdbl,
        const float* __restrict__ W, const float* __restrict__ bias,
        float* __restrict__ dt) {
    const int row = blockIdx.x;  // 0..4095
    __shared__ float r[DTRANK];
    if (threadIdx.x < DTRANK) r[threadIdx.x] = xdbl[(size_t)row * XDBL_W + threadIdx.x];
    __syncthreads();
    #pragma unroll
    for (int q = 0; q < 4; ++q) {
        const int d = (q << 8) + threadIdx.x;
        float acc = bias[d];
        const float* wp = W + (size_t)d * DTRANK;
        #pragma unroll
        for (int j = 0; j < DTRANK; ++j) acc = fmaf(r[j], wp[j], acc);
        dt[(size_t)row * DINNER + d] = (acc > 20.f) ? acc : log1pf(expf(acc));
    }
}

// ---------------- selective scan: one wave per (b,d); lane = state s ----------------
// h_n = exp(A_s*dt_n)*h_{n-1} + dt_n*u_n*B_n[s];  y_n = sum_s h_n[s]*C_n[s]
// y written transposed: yt[b][d][n] (coalesced 64-wide store every 64 steps)
__global__ __launch_bounds__(256) void scan_kernel(const float* __restrict__ dt,
        const float* __restrict__ u, const float* __restrict__ xdbl,
        const float* __restrict__ A_log, float* __restrict__ yt) {
    const int w = (blockIdx.x << 2) + (threadIdx.x >> 6);  // 0..2047
    const int lane = threadIdx.x & 63;
    const int b = w >> 10, d = w & (DINNER - 1);
    const float* dtp = dt + (size_t)b * NLEN * DINNER + d;
    const float* up  = u  + (size_t)b * NLEN * DINNER + d;
    const float* Bp  = xdbl + (size_t)b * NLEN * XDBL_W + DTRANK + lane;
    const float* Cp  = Bp + DSTATE;
    float* yp = yt + ((size_t)b * DINNER + d) * NLEN;
    const float kA = -expf(A_log[(size_t)d * DSTATE + lane]) * 1.44269504f;  // A_s*log2e
    float h = 0.f;
    for (int n0 = 0; n0 < NLEN; n0 += 64) {
        float ybuf = 0.f;
        #pragma unroll 4
        for (int j = 0; j < 64; ++j) {
            const int n = n0 + j;
            const float dtv = dtp[(size_t)n * DINNER];
            const float uv  = up[(size_t)n * DINNER];
            const float Bv  = Bp[(size_t)n * XDBL_W];
            const float Cv  = Cp[(size_t)n * XDBL_W];
            const float dA = exp2f(kA * dtv);
            h = fmaf(dA, h, dtv * uv * Bv);
            float yc = h * Cv;
            #pragma unroll
            for (int m = 32; m; m >>= 1) yc += __shfl_xor(yc, m);
            ybuf = (lane == j) ? yc : ybuf;
        }
        yp[n0 + lane] = ybuf;
    }
}

// ---------------- gate: yg = (yt^T + xi*D) * silu(z) ----------------
__global__ __launch_bounds__(256) void gate_kernel(const float* __restrict__ yt,
        const float* __restrict__ xi, const float* __restrict__ z,
        const float* __restrict__ Dv, float* __restrict__ yg) {
    const int g = blockIdx.x * 256 + threadIdx.x;
    const int d = g & (DINNER - 1);
    const int n = (g >> 10) & (NLEN - 1);
    const int b = g >> 21;
    const float yv = yt[((size_t)b * DINNER + d) * NLEN + n];
    const float zv = z[g];
    yg[g] = fmaf(xi[g], Dv[d], yv) * (zv / (1.f + expf(-zv)));
}

extern "C" void kernel_launch(void* const* d_in, const int* in_sizes, int n_in,
                              void* d_out, int out_size, void* d_ws, size_t ws_size,
                              hipStream_t stream) {
    const float* x         = (const float*)d_in[0];
    const float* norm_w    = (const float*)d_in[1];
    const float* norm_b    = (const float*)d_in[2];
    const float* in_proj_w = (const float*)d_in[3];
    const float* conv_w    = (const float*)d_in[4];
    const float* conv_b    = (const float*)d_in[5];
    const float* x_proj_w  = (const float*)d_in[6];
    const float* dt_proj_w = (const float*)d_in[7];
    const float* dt_proj_b = (const float*)d_in[8];
    const float* A_log     = (const float*)d_in[9];
    const float* Dvec      = (const float*)d_in[10];
    const float* out_proj_w= (const float*)d_in[11];
    float* out = (float*)d_out;
    float* ws  = (float*)d_ws;

    const size_t M4 = (size_t)4 * 1024 * 1024;   // 4M floats = 16MB
    float* xn_dt = ws;                 // xn (2M floats) then reused for dt (4M floats)
    float* xiraw = ws + M4;            // xi pre-conv; later reused for yg
    float* zbuf  = ws + 2 * M4;
    float* xibuf = ws + 3 * M4;        // xi post conv+silu
    float* xdbl  = ws + 4 * M4;        // 4096*160 = 655360 floats
    float* ytbuf = ws + 4 * M4 + (size_t)NROWS * XDBL_W;  // 4M floats
    // total: 21,626,880 floats = 86.5 MB

    ln_kernel<<<NROWS / 4, 256, 0, stream>>>(x, norm_w, norm_b, xn_dt);
    gemm_nt<<<dim3(2048 / 64, NROWS / 128), 256, 0, stream>>>(
        xn_dt, in_proj_w, NROWS, 2048, D_MODEL, xiraw, zbuf, DINNER);
    conv_kernel<<<(BSZ * NLEN * DINNER) / 256, 256, 0, stream>>>(
        xiraw, conv_w, conv_b, xibuf);
    gemm_nt<<<dim3((XDBL_W + 63) / 64, NROWS / 128), 256, 0, stream>>>(
        xibuf, x_proj_w, NROWS, XDBL_W, DINNER, xdbl, nullptr, XDBL_W);
    dt_kernel<<<NROWS, 256, 0, stream>>>(xdbl, dt_proj_w, dt_proj_b, xn_dt);
    scan_kernel<<<(BSZ * DINNER) / 4, 256, 0, stream>>>(
        xn_dt, xibuf, xdbl, A_log, ytbuf);
    gate_kernel<<<(BSZ * NLEN * DINNER) / 256, 256, 0, stream>>>(
        ytbuf, xibuf, zbuf, Dvec, xiraw);
    gemm_nt<<<dim3(D_MODEL / 64, NROWS / 128), 256, 0, stream>>>(
        xiraw, out_proj_w, NROWS, D_MODEL, DINNER, out, nullptr, D_MODEL);
}